// Round 9
// baseline (87.644 us; speedup 1.0000x reference)
//
#include <hip/hip_runtime.h>
#include <hip/hip_bf16.h>
#include <stdint.h>

#define NN 50000
#define NE 800000
#define DD 128
#define NBKT 782         // ceil(NN/64) dst buckets of 64 nodes
#define BCH 2048         // edges per workgroup in bscat
#define BGRID ((NE + BCH - 1) / BCH)   // 391
#define CAP 1280         // per-bucket slab capacity (mean 1023, sigma ~32)
#define SPILL_CAP 32768
#define GROWS 64         // gemm rows per block
#define GGRID ((NN + GROWS - 1) / GROWS)  // 782

typedef __attribute__((ext_vector_type(8))) unsigned short ushort8;
typedef __attribute__((ext_vector_type(8))) short short8;
typedef __attribute__((ext_vector_type(4))) float f32x4;

__device__ inline uint16_t f2bf(float f) {            // RNE f32->bf16
    uint32_t u = __float_as_uint(f);
    return (uint16_t)((u + 0x7fffu + ((u >> 16) & 1u)) >> 16);
}
__device__ inline float bf_lo(uint32_t u) { return __uint_as_float(u << 16); }
__device__ inline float bf_hi(uint32_t u) { return __uint_as_float(u & 0xffff0000u); }

// ---------- W f32 -> bf16 (row-major [j][k]) + zero the bucket counters ----------
__global__ __launch_bounds__(256) void wconv_k(const float* __restrict__ W,
                                               uint16_t* __restrict__ Wb,
                                               int* __restrict__ cntg) {
    int t = threadIdx.x;
    if (blockIdx.x == 0) {                         // zero cntg[NBKT] + scnt (contiguous)
        for (int k = t; k < NBKT + 4; k += 256) cntg[k] = 0;
    }
    int i = blockIdx.x * 256 + t;
    if (i < DD * DD) Wb[i] = f2bf(W[i]);
}

// ---------- MFMA GEMM: h = x @ W^T (bf16 mfma, f32 acc) + s/d projections ----------
// block: 64 rows x 128 cols, 4 waves. wave wid owns rows r0 + wid*16 .. +16, ALL 128 cols.
// A frag (16x32): lane l -> row l&15, k = (l>>4)*8..+8.  B frag: col l&15, same k slice.
// C/D: col = l&15, row = (l>>4)*4 + reg.
__global__ __launch_bounds__(256) void gemm_mfma_k(const float* __restrict__ x,
                                                   const uint16_t* __restrict__ Wb,
                                                   const float* __restrict__ a,
                                                   uint16_t* __restrict__ hb,
                                                   float* __restrict__ sArr,
                                                   float* __restrict__ dArr) {
    __shared__ __align__(16) uint16_t hs[GROWS][136];   // 17.4 KB
    const int t = threadIdx.x, l = t & 63, wid = t >> 6;
    const int r0 = blockIdx.x * GROWS;
    const int lr = l & 15, lk = l >> 4;

    f32x4 acc[8];
    #pragma unroll
    for (int c = 0; c < 8; ++c) acc[c] = f32x4{0.f, 0.f, 0.f, 0.f};

    const int arow = r0 + wid * 16 + lr;
    const bool rok = arow < NN;
    const float* xp = x + (size_t)arow * DD + lk * 8;

    #pragma unroll
    for (int kc = 0; kc < 4; ++kc) {
        short8 af;
        if (rok) {
            float4 v0 = *(const float4*)(xp + kc * 32);
            float4 v1 = *(const float4*)(xp + kc * 32 + 4);
            af[0] = (short)f2bf(v0.x); af[1] = (short)f2bf(v0.y);
            af[2] = (short)f2bf(v0.z); af[3] = (short)f2bf(v0.w);
            af[4] = (short)f2bf(v1.x); af[5] = (short)f2bf(v1.y);
            af[6] = (short)f2bf(v1.z); af[7] = (short)f2bf(v1.w);
        } else {
            af = short8{0,0,0,0,0,0,0,0};
        }
        #pragma unroll
        for (int c = 0; c < 8; ++c) {
            int col = c * 16 + lr;
            short8 bf_ = *(const short8*)(Wb + (size_t)col * DD + kc * 32 + lk * 8);
            acc[c] = __builtin_amdgcn_mfma_f32_16x16x32_bf16(af, bf_, acc[c], 0, 0, 0);
        }
    }

    // s/d projections: wave-local (wave owns full 128-col row slices)
    float avs[8], avd[8];
    #pragma unroll
    for (int c = 0; c < 8; ++c) {
        avs[c] = a[c * 16 + lr];
        avd[c] = a[DD + c * 16 + lr];
    }
    #pragma unroll
    for (int i = 0; i < 4; ++i) {
        float ps = 0.f, pd = 0.f;
        #pragma unroll
        for (int c = 0; c < 8; ++c) {
            ps = fmaf(acc[c][i], avs[c], ps);
            pd = fmaf(acc[c][i], avd[c], pd);
        }
        #pragma unroll
        for (int o = 8; o > 0; o >>= 1) {
            ps += __shfl_xor(ps, o);
            pd += __shfl_xor(pd, o);
        }
        if (lr == 0) {
            int row = r0 + wid * 16 + lk * 4 + i;
            if (row < NN) { sArr[row] = ps; dArr[row] = pd; }
        }
    }
    // h -> LDS (bf16)
    #pragma unroll
    for (int c = 0; c < 8; ++c)
        #pragma unroll
        for (int i = 0; i < 4; ++i)
            hs[wid * 16 + lk * 4 + i][c * 16 + lr] = f2bf(acc[c][i]);
    __syncthreads();

    // coalesced writeback: thread t -> row t>>2, cols (t&3)*32 .. +32
    {
        int row = t >> 2, cb = (t & 3) * 32;
        int grow = r0 + row;
        if (grow < NN) {
            #pragma unroll
            for (int k = 0; k < 4; ++k) {
                ushort8 v = *(const ushort8*)&hs[row][cb + k * 8];
                *(ushort8*)(hb + (size_t)grow * DD + cb + k * 8) = v;
            }
        }
    }
}

// ---------- bscat: slim slab scatter of 4B records. rec = (dlocal<<16)|src ----------
__global__ __launch_bounds__(256) void bscat_k(const int* __restrict__ src,
                                               const int* __restrict__ dst,
                                               int* __restrict__ cntg,
                                               int* __restrict__ spill_cnt,
                                               uint32_t* __restrict__ rec,
                                               uint2* __restrict__ spill) {
    __shared__ int lh[NBKT];
    __shared__ int gb[NBKT];
    int t = threadIdx.x;
    for (int k = t; k < NBKT; k += 256) lh[k] = 0;
    __syncthreads();
    int base = blockIdx.x * BCH;
    unsigned pk[8]; int bk[8];
    #pragma unroll
    for (int i = 0; i < 8; ++i) {
        int idx = base + i * 256 + t;
        if (idx < NE) {
            int s_ = src[idx], d_ = dst[idx];
            bk[i] = d_ >> 6;
            pk[i] = ((unsigned)(d_ & 63) << 16) | (unsigned)s_;
            atomicAdd(&lh[bk[i]], 1);
        } else bk[i] = -1;
    }
    __syncthreads();
    for (int k = t; k < NBKT; k += 256) {
        int c = lh[k];
        lh[k] = 0;                       // becomes local cursor
        if (c) gb[k] = atomicAdd(&cntg[k], c);
    }
    __syncthreads();
    #pragma unroll
    for (int i = 0; i < 8; ++i) {
        if (bk[i] >= 0) {
            int sl = atomicAdd(&lh[bk[i]], 1);
            int p = gb[bk[i]] + sl;
            if (p < CAP) {
                rec[(size_t)bk[i] * CAP + p] = pk[i];
            } else {
                int sp = atomicAdd(spill_cnt, 1);
                if (sp < SPILL_CAP)
                    spill[sp] = make_uint2(pk[i] & 0xffffu,
                                           (unsigned)(bk[i] * 64 + (int)(pk[i] >> 16)));
            }
        }
    }
}

// ---------- agg: one 512-thread WG per bucket; LDS sort + fused e-compute ----------
__global__ __launch_bounds__(512) void bsort_agg_k(const uint32_t* __restrict__ hb,
                                                   const float* __restrict__ sA,
                                                   const float* __restrict__ dA,
                                                   const int* __restrict__ cntg,
                                                   const uint32_t* __restrict__ rec,
                                                   float* __restrict__ out) {
    __shared__ uint32_t srt[CAP];   // 5 KB
    __shared__ float    eL[CAP];    // 5 KB
    __shared__ float dAl[64];
    __shared__ int h64[64];
    __shared__ int s65[65];
    __shared__ int curw[64];
    int t = threadIdx.x, l = t & 63, wid = t >> 6;
    int b = blockIdx.x;
    int cnt = cntg[b]; if (cnt > CAP) cnt = CAP;
    int beg = b * CAP;
    int n0 = b * 64;
    if (t < 64) {
        h64[t] = 0;
        int n = n0 + t;
        dAl[t] = (n < NN) ? dA[n] : 0.f;
    }
    __syncthreads();

    // histogram (cache records in registers: cnt<=1280 -> <=3 per thread)
    uint32_t rc[3]; int nrc = 0;
    for (int j = t; j < cnt; j += 512) {
        uint32_t r = rec[beg + j];
        rc[nrc++] = r;
        atomicAdd(&h64[r >> 16], 1);
    }
    __syncthreads();
    if (wid == 0) {
        int v = h64[l];
        int inc = v;
        #pragma unroll
        for (int o = 1; o < 64; o <<= 1) {
            int nb = __shfl_up(inc, o);
            if (l >= o) inc += nb;
        }
        s65[l + 1] = inc;
        if (l == 0) s65[0] = 0;
        curw[l] = inc - v;
    }
    __syncthreads();
    // scatter + fused sigmoid (once per record, one thread each)
    for (int k = 0; k < nrc; ++k) {
        uint32_t r = rc[k];
        int d = (int)(r >> 16);
        int p = atomicAdd(&curw[d], 1);
        float z = sA[r & 0xffffu] + dAl[d];
        srt[p] = r;
        eL[p] = 1.f / (1.f + __expf(-z));
    }
    __syncthreads();
    #pragma unroll 1
    for (int rr = 0; rr < 8; ++rr) {
        int d = wid * 8 + rr;
        int n = n0 + d;
        if (n >= NN) break;
        int js = s65[d], je = s65[d + 1];
        float2 a0 = {0.f,0.f}, a1 = {0.f,0.f}, a2 = {0.f,0.f}, a3 = {0.f,0.f};
        int j = js;
        for (; j + 7 < je; j += 8) {
            uint32_t r0 = srt[j],   r1 = srt[j+1], r2 = srt[j+2], r3 = srt[j+3];
            uint32_t r4 = srt[j+4], r5 = srt[j+5], r6 = srt[j+6], r7 = srt[j+7];
            uint32_t u0 = hb[(size_t)(r0 & 0xffffu) * 64 + l];
            uint32_t u1 = hb[(size_t)(r1 & 0xffffu) * 64 + l];
            uint32_t u2 = hb[(size_t)(r2 & 0xffffu) * 64 + l];
            uint32_t u3 = hb[(size_t)(r3 & 0xffffu) * 64 + l];
            uint32_t u4 = hb[(size_t)(r4 & 0xffffu) * 64 + l];
            uint32_t u5 = hb[(size_t)(r5 & 0xffffu) * 64 + l];
            uint32_t u6 = hb[(size_t)(r6 & 0xffffu) * 64 + l];
            uint32_t u7 = hb[(size_t)(r7 & 0xffffu) * 64 + l];
            float e0 = eL[j],   e1 = eL[j+1], e2 = eL[j+2], e3 = eL[j+3];
            float e4 = eL[j+4], e5 = eL[j+5], e6 = eL[j+6], e7 = eL[j+7];
            a0.x = fmaf(e0, bf_lo(u0), a0.x); a0.y = fmaf(e0, bf_hi(u0), a0.y);
            a1.x = fmaf(e1, bf_lo(u1), a1.x); a1.y = fmaf(e1, bf_hi(u1), a1.y);
            a2.x = fmaf(e2, bf_lo(u2), a2.x); a2.y = fmaf(e2, bf_hi(u2), a2.y);
            a3.x = fmaf(e3, bf_lo(u3), a3.x); a3.y = fmaf(e3, bf_hi(u3), a3.y);
            a0.x = fmaf(e4, bf_lo(u4), a0.x); a0.y = fmaf(e4, bf_hi(u4), a0.y);
            a1.x = fmaf(e5, bf_lo(u5), a1.x); a1.y = fmaf(e5, bf_hi(u5), a1.y);
            a2.x = fmaf(e6, bf_lo(u6), a2.x); a2.y = fmaf(e6, bf_hi(u6), a2.y);
            a3.x = fmaf(e7, bf_lo(u7), a3.x); a3.y = fmaf(e7, bf_hi(u7), a3.y);
        }
        for (; j + 3 < je; j += 4) {
            uint32_t r0 = srt[j], r1 = srt[j+1], r2 = srt[j+2], r3 = srt[j+3];
            float e0 = eL[j], e1 = eL[j+1], e2 = eL[j+2], e3 = eL[j+3];
            uint32_t u0 = hb[(size_t)(r0 & 0xffffu) * 64 + l];
            uint32_t u1 = hb[(size_t)(r1 & 0xffffu) * 64 + l];
            uint32_t u2 = hb[(size_t)(r2 & 0xffffu) * 64 + l];
            uint32_t u3 = hb[(size_t)(r3 & 0xffffu) * 64 + l];
            a0.x = fmaf(e0, bf_lo(u0), a0.x); a0.y = fmaf(e0, bf_hi(u0), a0.y);
            a1.x = fmaf(e1, bf_lo(u1), a1.x); a1.y = fmaf(e1, bf_hi(u1), a1.y);
            a2.x = fmaf(e2, bf_lo(u2), a2.x); a2.y = fmaf(e2, bf_hi(u2), a2.y);
            a3.x = fmaf(e3, bf_lo(u3), a3.x); a3.y = fmaf(e3, bf_hi(u3), a3.y);
        }
        for (; j < je; ++j) {
            uint32_t r0 = srt[j];
            float e0 = eL[j];
            uint32_t u0 = hb[(size_t)(r0 & 0xffffu) * 64 + l];
            a0.x = fmaf(e0, bf_lo(u0), a0.x); a0.y = fmaf(e0, bf_hi(u0), a0.y);
        }
        float2 res;
        res.x = (a0.x + a1.x) + (a2.x + a3.x);
        res.y = (a0.y + a1.y) + (a2.y + a3.y);
        ((float2*)out)[(size_t)n * 64 + l] = res;
    }
}

// ---------- spill drain (normally 0 records) ----------
__global__ __launch_bounds__(256) void spill_k(const int* __restrict__ spill_cnt,
                                               const uint2* __restrict__ spill,
                                               const float* __restrict__ sA,
                                               const float* __restrict__ dA,
                                               const uint32_t* __restrict__ hb,
                                               float* __restrict__ out) {
    int n = *spill_cnt; if (n > SPILL_CAP) n = SPILL_CAP;
    int w = blockIdx.x * 4 + (threadIdx.x >> 6), l = threadIdx.x & 63;
    for (int i = w; i < n; i += 32) {
        uint2 r = spill[i];
        float z = sA[r.x] + dA[r.y];
        float e = 1.f / (1.f + __expf(-z));
        uint32_t u = hb[(size_t)r.x * 64 + l];
        atomicAdd(&out[(size_t)r.y * DD + 2 * l],     e * bf_lo(u));
        atomicAdd(&out[(size_t)r.y * DD + 2 * l + 1], e * bf_hi(u));
    }
}

// ---------- fallback: direct atomic scatter-add ----------
__global__ __launch_bounds__(256) void edge_atomic_k(const int* __restrict__ src, const int* __restrict__ dst,
                                                     const float* __restrict__ sArr, const float* __restrict__ dArr,
                                                     const uint32_t* __restrict__ hb, float* __restrict__ out) {
    int wid = threadIdx.x >> 6, l = threadIdx.x & 63;
    int e = blockIdx.x * 4 + wid;
    if (e >= NE) return;
    int sv = src[e], dv = dst[e];
    float z = sArr[sv] + dArr[dv];
    float ev = 1.0f / (1.0f + __expf(-z));
    uint32_t u = hb[(size_t)sv * 64 + l];
    atomicAdd(&out[(size_t)dv * DD + 2 * l],     ev * bf_lo(u));
    atomicAdd(&out[(size_t)dv * DD + 2 * l + 1], ev * bf_hi(u));
}

extern "C" void kernel_launch(void* const* d_in, const int* in_sizes, int n_in,
                              void* d_out, int out_size, void* d_ws, size_t ws_size,
                              hipStream_t stream) {
    const float* x  = (const float*)d_in[0];
    const float* W  = (const float*)d_in[1];
    const float* a  = (const float*)d_in[2];
    const int* src  = (const int*)d_in[3];
    const int* dst  = (const int*)d_in[4];
    float* out = (float*)d_out;

    char* p = (char*)d_ws;
    uint16_t* hb = (uint16_t*)p;            p += (size_t)NN * DD * 2;       // 12.8 MB
    uint16_t* Wb = (uint16_t*)p;            p += (size_t)DD * DD * 2;       // 32 KB
    float* sA    = (float*)p;               p += (size_t)NN * 4;
    float* dA    = (float*)p;               p += (size_t)NN * 4;
    int*   cntg  = (int*)p;                 p += (size_t)NBKT * 4;
    int*   scnt  = (int*)p;                 p += 16;
    uint32_t* rec = (uint32_t*)(((uintptr_t)p + 15) & ~(uintptr_t)15);
    p = (char*)(rec + (size_t)NBKT * CAP);                                   // 4.0 MB
    uint2* spill = (uint2*)p;               p += (size_t)SPILL_CAP * 8;      // 0.25 MB
    size_t need  = (size_t)(p - (char*)d_ws);

    if (ws_size >= need) {
        wconv_k<<<64, 256, 0, stream>>>(W, Wb, cntg);    // also zeros cntg+scnt
        gemm_mfma_k<<<GGRID, 256, 0, stream>>>(x, Wb, a, hb, sA, dA);
        bscat_k<<<BGRID, 256, 0, stream>>>(src, dst, cntg, scnt, rec, spill);
        bsort_agg_k<<<NBKT, 512, 0, stream>>>((const uint32_t*)hb, sA, dA, cntg, rec, out);
        spill_k<<<8, 256, 0, stream>>>(scnt, spill, sA, dA, (const uint32_t*)hb, out);
    } else {
        hipMemsetAsync(out, 0, sizeof(float) * (size_t)NN * DD, stream);
        wconv_k<<<64, 256, 0, stream>>>(W, Wb, cntg);
        gemm_mfma_k<<<GGRID, 256, 0, stream>>>(x, Wb, a, hb, sA, dA);
        edge_atomic_k<<<NE / 4, 256, 0, stream>>>(src, dst, sA, dA, (const uint32_t*)hb, out);
    }
}

// Round 10
// 72.634 us; speedup vs baseline: 1.2066x; 1.2066x over previous
//
#include <hip/hip_runtime.h>
#include <hip/hip_bf16.h>
#include <stdint.h>

#define NN 50000
#define NE 800000
#define DD 128
#define NBKT 782         // ceil(NN/64) dst buckets of 64 nodes
#define BCH 4096         // edges per workgroup in bscat
#define BGRID ((NE + BCH - 1) / BCH)   // 196
#define CAP 1280         // per-bucket slab capacity (mean 1023, sigma ~32)
#define SPILL_CAP 32768
#define GROWS 64         // gemm rows per block
#define GGRID ((NN + GROWS - 1) / GROWS)  // 782

typedef __attribute__((ext_vector_type(8))) unsigned short ushort8;
typedef __attribute__((ext_vector_type(8))) short short8;
typedef __attribute__((ext_vector_type(4))) float f32x4;

__device__ inline uint32_t cvtpk(float lo, float hi) {   // bf16(lo) in [15:0], bf16(hi) in [31:16], RNE
    uint32_t r;
    asm("v_cvt_pk_bf16_f32 %0, %1, %2" : "=v"(r) : "v"(lo), "v"(hi));
    return r;
}
__device__ inline float bf_lo(uint32_t u) { return __uint_as_float(u << 16); }
__device__ inline float bf_hi(uint32_t u) { return __uint_as_float(u & 0xffff0000u); }

// ---------- prep: W f32 -> bf16 + zero bucket counters ----------
__global__ __launch_bounds__(256) void prep_k(const float* __restrict__ W,
                                              uint16_t* __restrict__ Wb,
                                              int* __restrict__ cntg) {
    int t = threadIdx.x;
    if (blockIdx.x == 0) {
        for (int k = t; k < NBKT + 4; k += 256) cntg[k] = 0;   // cntg + scnt
    }
    int i = blockIdx.x * 256 + t;
    if (i < DD * DD) {
        uint32_t u = __float_as_uint(W[i]);
        Wb[i] = (uint16_t)((u + 0x7fffu + ((u >> 16) & 1u)) >> 16);
    }
}

// ---------- fused: gemm (blocks < GGRID) || bscat (blocks >= GGRID) ----------
// gemm: block = 64 rows x 128 cols, 4 waves, NO LDS. Wave wid: rows r0+wid*16..+16, all cols.
// h stored PERMUTED: hb[row*128 + lr*8 + c] = h[row][c*16+lr]  (lane-contiguous ushort8 stores).
__global__ __launch_bounds__(256) void fused_k(const float* __restrict__ x,
                                               const uint16_t* __restrict__ Wb,
                                               const float* __restrict__ a,
                                               const int* __restrict__ src,
                                               const int* __restrict__ dst,
                                               uint16_t* __restrict__ hb,
                                               float* __restrict__ sArr,
                                               float* __restrict__ dArr,
                                               int* __restrict__ cntg,
                                               int* __restrict__ scnt,
                                               uint32_t* __restrict__ rec,
                                               uint2* __restrict__ spill) {
    __shared__ int lh[NBKT];
    __shared__ int gb[NBKT];
    const int t = threadIdx.x;

    if ((int)blockIdx.x < GGRID) {
        // ---------------- GEMM role ----------------
        const int l = t & 63, wid = t >> 6;
        const int r0 = blockIdx.x * GROWS;
        const int lr = l & 15, lk = l >> 4;

        f32x4 acc[8];
        #pragma unroll
        for (int c = 0; c < 8; ++c) acc[c] = f32x4{0.f, 0.f, 0.f, 0.f};

        const int arow = r0 + wid * 16 + lr;
        const int lrow = (arow < NN) ? arow : (NN - 1);        // clamp loads; guard stores
        const float* xp = x + (size_t)lrow * DD + lk * 8;

        #pragma unroll
        for (int kc = 0; kc < 4; ++kc) {
            float4 v0 = *(const float4*)(xp + kc * 32);
            float4 v1 = *(const float4*)(xp + kc * 32 + 4);
            union { uint32_t u[4]; short8 s; } A;
            A.u[0] = cvtpk(v0.x, v0.y); A.u[1] = cvtpk(v0.z, v0.w);
            A.u[2] = cvtpk(v1.x, v1.y); A.u[3] = cvtpk(v1.z, v1.w);
            #pragma unroll
            for (int c = 0; c < 8; ++c) {
                int col = c * 16 + lr;
                short8 bf_ = *(const short8*)(Wb + (size_t)col * DD + kc * 32 + lk * 8);
                acc[c] = __builtin_amdgcn_mfma_f32_16x16x32_bf16(A.s, bf_, acc[c], 0, 0, 0);
            }
        }

        // s/d projections (wave-local shuffle reduce over the 16 lr lanes)
        float avs[8], avd[8];
        #pragma unroll
        for (int c = 0; c < 8; ++c) {
            avs[c] = a[c * 16 + lr];
            avd[c] = a[DD + c * 16 + lr];
        }
        #pragma unroll
        for (int i = 0; i < 4; ++i) {
            float ps = 0.f, pd = 0.f;
            #pragma unroll
            for (int c = 0; c < 8; ++c) {
                ps = fmaf(acc[c][i], avs[c], ps);
                pd = fmaf(acc[c][i], avd[c], pd);
            }
            #pragma unroll
            for (int o = 8; o > 0; o >>= 1) {
                ps += __shfl_xor(ps, o);
                pd += __shfl_xor(pd, o);
            }
            int row = r0 + wid * 16 + lk * 4 + i;
            if (lr == 0 && row < NN) { sArr[row] = ps; dArr[row] = pd; }
        }

        // permuted h writeback: 4 x ushort8 per lane, no LDS
        #pragma unroll
        for (int i = 0; i < 4; ++i) {
            int row = r0 + wid * 16 + lk * 4 + i;
            if (row < NN) {
                union { uint32_t u[4]; ushort8 s; } H;
                H.u[0] = cvtpk(acc[0][i], acc[1][i]);
                H.u[1] = cvtpk(acc[2][i], acc[3][i]);
                H.u[2] = cvtpk(acc[4][i], acc[5][i]);
                H.u[3] = cvtpk(acc[6][i], acc[7][i]);
                *(ushort8*)(hb + (size_t)row * DD + lr * 8) = H.s;
            }
        }
    } else {
        // ---------------- BSCAT role ----------------
        int bb = blockIdx.x - GGRID;
        for (int k = t; k < NBKT; k += 256) lh[k] = 0;
        __syncthreads();
        int base = bb * BCH;
        unsigned pk[16]; int bk[16];
        #pragma unroll
        for (int i = 0; i < 16; ++i) {
            int idx = base + i * 256 + t;
            if (idx < NE) {
                int s_ = src[idx], d_ = dst[idx];
                bk[i] = d_ >> 6;
                pk[i] = ((unsigned)(d_ & 63) << 16) | (unsigned)s_;
                atomicAdd(&lh[bk[i]], 1);
            } else bk[i] = -1;
        }
        __syncthreads();
        for (int k = t; k < NBKT; k += 256) {
            int c = lh[k];
            lh[k] = 0;                       // becomes local cursor
            if (c) gb[k] = atomicAdd(&cntg[k], c);
        }
        __syncthreads();
        #pragma unroll
        for (int i = 0; i < 16; ++i) {
            if (bk[i] >= 0) {
                int sl = atomicAdd(&lh[bk[i]], 1);
                int p = gb[bk[i]] + sl;
                if (p < CAP) {
                    rec[(size_t)bk[i] * CAP + p] = pk[i];
                } else {
                    int sp = atomicAdd(scnt, 1);
                    if (sp < SPILL_CAP)
                        spill[sp] = make_uint2(pk[i] & 0xffffu,
                                               (unsigned)(bk[i] * 64 + (int)(pk[i] >> 16)));
                }
            }
        }
    }
}

// ---------- agg: one 512-thread WG per bucket; LDS sort + fused e + inline spill ----------
__global__ __launch_bounds__(512) void bsort_agg_k(const uint32_t* __restrict__ hb,
                                                   const float* __restrict__ sA,
                                                   const float* __restrict__ dA,
                                                   const int* __restrict__ cntg,
                                                   const uint32_t* __restrict__ rec,
                                                   const int* __restrict__ scnt,
                                                   const uint2* __restrict__ spill,
                                                   float* __restrict__ out) {
    __shared__ uint32_t srt[CAP];   // 5 KB
    __shared__ float    eL[CAP];    // 5 KB
    __shared__ float dAl[64];
    __shared__ int h64[64];
    __shared__ int s65[65];
    __shared__ int curw[64];
    int t = threadIdx.x, l = t & 63, wid = t >> 6;
    int b = blockIdx.x;
    int cnt = cntg[b]; if (cnt > CAP) cnt = CAP;
    int beg = b * CAP;
    int n0 = b * 64;
    int ns = *scnt; if (ns > SPILL_CAP) ns = SPILL_CAP;
    if (t < 64) {
        h64[t] = 0;
        int n = n0 + t;
        dAl[t] = (n < NN) ? dA[n] : 0.f;
    }
    __syncthreads();

    // histogram (cache records in registers: cnt<=1280 -> <=3 per thread)
    uint32_t rc[3]; int nrc = 0;
    for (int j = t; j < cnt; j += 512) {
        uint32_t r = rec[beg + j];
        rc[nrc++] = r;
        atomicAdd(&h64[r >> 16], 1);
    }
    __syncthreads();
    if (wid == 0) {
        int v = h64[l];
        int inc = v;
        #pragma unroll
        for (int o = 1; o < 64; o <<= 1) {
            int nb = __shfl_up(inc, o);
            if (l >= o) inc += nb;
        }
        s65[l + 1] = inc;
        if (l == 0) s65[0] = 0;
        curw[l] = inc - v;
    }
    __syncthreads();
    // scatter + fused sigmoid (once per record)
    for (int k = 0; k < nrc; ++k) {
        uint32_t r = rc[k];
        int d = (int)(r >> 16);
        int p = atomicAdd(&curw[d], 1);
        float z = sA[r & 0xffffu] + dAl[d];
        srt[p] = r;
        eL[p] = 1.f / (1.f + __expf(-z));
    }
    __syncthreads();
    int colx = 32 * (l & 3) + (l >> 2);     // permuted-layout column for res.x; res.y -> +16
    #pragma unroll 1
    for (int rr = 0; rr < 8; ++rr) {
        int d = wid * 8 + rr;
        int n = n0 + d;
        if (n >= NN) break;
        int js = s65[d], je = s65[d + 1];
        float2 a0 = {0.f,0.f}, a1 = {0.f,0.f}, a2 = {0.f,0.f}, a3 = {0.f,0.f};
        int j = js;
        for (; j + 7 < je; j += 8) {
            uint32_t r0 = srt[j],   r1 = srt[j+1], r2 = srt[j+2], r3 = srt[j+3];
            uint32_t r4 = srt[j+4], r5 = srt[j+5], r6 = srt[j+6], r7 = srt[j+7];
            uint32_t u0 = hb[(size_t)(r0 & 0xffffu) * 64 + l];
            uint32_t u1 = hb[(size_t)(r1 & 0xffffu) * 64 + l];
            uint32_t u2 = hb[(size_t)(r2 & 0xffffu) * 64 + l];
            uint32_t u3 = hb[(size_t)(r3 & 0xffffu) * 64 + l];
            uint32_t u4 = hb[(size_t)(r4 & 0xffffu) * 64 + l];
            uint32_t u5 = hb[(size_t)(r5 & 0xffffu) * 64 + l];
            uint32_t u6 = hb[(size_t)(r6 & 0xffffu) * 64 + l];
            uint32_t u7 = hb[(size_t)(r7 & 0xffffu) * 64 + l];
            float e0 = eL[j],   e1 = eL[j+1], e2 = eL[j+2], e3 = eL[j+3];
            float e4 = eL[j+4], e5 = eL[j+5], e6 = eL[j+6], e7 = eL[j+7];
            a0.x = fmaf(e0, bf_lo(u0), a0.x); a0.y = fmaf(e0, bf_hi(u0), a0.y);
            a1.x = fmaf(e1, bf_lo(u1), a1.x); a1.y = fmaf(e1, bf_hi(u1), a1.y);
            a2.x = fmaf(e2, bf_lo(u2), a2.x); a2.y = fmaf(e2, bf_hi(u2), a2.y);
            a3.x = fmaf(e3, bf_lo(u3), a3.x); a3.y = fmaf(e3, bf_hi(u3), a3.y);
            a0.x = fmaf(e4, bf_lo(u4), a0.x); a0.y = fmaf(e4, bf_hi(u4), a0.y);
            a1.x = fmaf(e5, bf_lo(u5), a1.x); a1.y = fmaf(e5, bf_hi(u5), a1.y);
            a2.x = fmaf(e6, bf_lo(u6), a2.x); a2.y = fmaf(e6, bf_hi(u6), a2.y);
            a3.x = fmaf(e7, bf_lo(u7), a3.x); a3.y = fmaf(e7, bf_hi(u7), a3.y);
        }
        for (; j + 3 < je; j += 4) {
            uint32_t r0 = srt[j], r1 = srt[j+1], r2 = srt[j+2], r3 = srt[j+3];
            float e0 = eL[j], e1 = eL[j+1], e2 = eL[j+2], e3 = eL[j+3];
            uint32_t u0 = hb[(size_t)(r0 & 0xffffu) * 64 + l];
            uint32_t u1 = hb[(size_t)(r1 & 0xffffu) * 64 + l];
            uint32_t u2 = hb[(size_t)(r2 & 0xffffu) * 64 + l];
            uint32_t u3 = hb[(size_t)(r3 & 0xffffu) * 64 + l];
            a0.x = fmaf(e0, bf_lo(u0), a0.x); a0.y = fmaf(e0, bf_hi(u0), a0.y);
            a1.x = fmaf(e1, bf_lo(u1), a1.x); a1.y = fmaf(e1, bf_hi(u1), a1.y);
            a2.x = fmaf(e2, bf_lo(u2), a2.x); a2.y = fmaf(e2, bf_hi(u2), a2.y);
            a3.x = fmaf(e3, bf_lo(u3), a3.x); a3.y = fmaf(e3, bf_hi(u3), a3.y);
        }
        for (; j < je; ++j) {
            uint32_t r0 = srt[j];
            float e0 = eL[j];
            uint32_t u0 = hb[(size_t)(r0 & 0xffffu) * 64 + l];
            a0.x = fmaf(e0, bf_lo(u0), a0.x); a0.y = fmaf(e0, bf_hi(u0), a0.y);
        }
        float2 res;
        res.x = (a0.x + a1.x) + (a2.x + a3.x);
        res.y = (a0.y + a1.y) + (a2.y + a3.y);
        if (ns > 0) {                       // inline spill drain (statistically empty)
            for (int i = 0; i < ns; ++i) {
                uint2 sp = spill[i];
                if ((int)sp.y == n) {
                    float z = sA[sp.x] + dAl[d];
                    float e = 1.f / (1.f + __expf(-z));
                    uint32_t u = hb[(size_t)sp.x * 64 + l];
                    res.x = fmaf(e, bf_lo(u), res.x);
                    res.y = fmaf(e, bf_hi(u), res.y);
                }
            }
        }
        float* orow = out + (size_t)n * DD;
        orow[colx]      = res.x;
        orow[colx + 16] = res.y;
    }
}

// ---------- fallback: direct atomic scatter-add (permuted hb layout) ----------
__global__ __launch_bounds__(256) void edge_atomic_k(const int* __restrict__ src, const int* __restrict__ dst,
                                                     const float* __restrict__ sArr, const float* __restrict__ dArr,
                                                     const uint32_t* __restrict__ hb, float* __restrict__ out) {
    int wid = threadIdx.x >> 6, l = threadIdx.x & 63;
    int e = blockIdx.x * 4 + wid;
    if (e >= NE) return;
    int sv = src[e], dv = dst[e];
    float z = sArr[sv] + dArr[dv];
    float ev = 1.0f / (1.0f + __expf(-z));
    uint32_t u = hb[(size_t)sv * 64 + l];
    int colx = 32 * (l & 3) + (l >> 2);
    atomicAdd(&out[(size_t)dv * DD + colx],      ev * bf_lo(u));
    atomicAdd(&out[(size_t)dv * DD + colx + 16], ev * bf_hi(u));
}

extern "C" void kernel_launch(void* const* d_in, const int* in_sizes, int n_in,
                              void* d_out, int out_size, void* d_ws, size_t ws_size,
                              hipStream_t stream) {
    const float* x  = (const float*)d_in[0];
    const float* W  = (const float*)d_in[1];
    const float* a  = (const float*)d_in[2];
    const int* src  = (const int*)d_in[3];
    const int* dst  = (const int*)d_in[4];
    float* out = (float*)d_out;

    char* p = (char*)d_ws;
    uint16_t* hb = (uint16_t*)p;            p += (size_t)NN * DD * 2;       // 12.8 MB
    uint16_t* Wb = (uint16_t*)p;            p += (size_t)DD * DD * 2;       // 32 KB
    float* sA    = (float*)p;               p += (size_t)NN * 4;
    float* dA    = (float*)p;               p += (size_t)NN * 4;
    int*   cntg  = (int*)p;                 p += (size_t)NBKT * 4;
    int*   scnt  = (int*)p;                 p += 16;
    uint32_t* rec = (uint32_t*)(((uintptr_t)p + 15) & ~(uintptr_t)15);
    p = (char*)(rec + (size_t)NBKT * CAP);                                   // 4.0 MB
    uint2* spill = (uint2*)p;               p += (size_t)SPILL_CAP * 8;      // 0.25 MB
    size_t need  = (size_t)(p - (char*)d_ws);

    if (ws_size >= need) {
        prep_k<<<64, 256, 0, stream>>>(W, Wb, cntg);                 // zeros cntg+scnt
        fused_k<<<GGRID + BGRID, 256, 0, stream>>>(x, Wb, a, src, dst,
                                                   hb, sA, dA, cntg, scnt, rec, spill);
        bsort_agg_k<<<NBKT, 512, 0, stream>>>((const uint32_t*)hb, sA, dA, cntg, rec,
                                              scnt, spill, out);
    } else {
        hipMemsetAsync(out, 0, sizeof(float) * (size_t)NN * DD, stream);
        prep_k<<<64, 256, 0, stream>>>(W, Wb, cntg);
        fused_k<<<GGRID, 256, 0, stream>>>(x, Wb, a, src, dst,
                                           hb, sA, dA, cntg, scnt, rec, spill);
        edge_atomic_k<<<NE / 4, 256, 0, stream>>>(src, dst, sA, dA, (const uint32_t*)hb, out);
    }
}